// Round 5
// baseline (349.979 us; speedup 1.0000x reference)
//
#include <hip/hip_runtime.h>
#include <hip/hip_bf16.h>
#include <stdint.h>

#define OUT_N 4096
#define IN_N  4096
#define BATCH 2048
#define KHALF 2049   // IN/2 + 1

typedef __bf16 bf16x8 __attribute__((ext_vector_type(8)));
typedef float  f32x4  __attribute__((ext_vector_type(4)));

__device__ __forceinline__ unsigned short f2bf(float f) {
  unsigned int u = __builtin_bit_cast(unsigned int, f);
  u += 0x7FFFu + ((u >> 16) & 1u);   // round-to-nearest-even
  return (unsigned short)(u >> 16);
}

// ---------------------------------------------------------------------------
// complex helpers
// ---------------------------------------------------------------------------
__device__ __forceinline__ float2 cmul(float2 a, float2 b) {
  return make_float2(a.x * b.x - a.y * b.y, a.x * b.y + a.y * b.x);
}
__device__ __forceinline__ float2 cadd(float2 a, float2 b) { return make_float2(a.x + b.x, a.y + b.y); }
__device__ __forceinline__ float2 csub(float2 a, float2 b) { return make_float2(a.x - b.x, a.y - b.y); }
__device__ __forceinline__ float2 muli(float2 a) { return make_float2(-a.y, a.x); }  // *e^{+i pi/2}

// inverse DFT4 (w = +i)
__device__ __forceinline__ void dft4i(float2& x0, float2& x1, float2& x2, float2& x3) {
  float2 t0 = cadd(x0, x2), t1 = csub(x0, x2);
  float2 t2 = cadd(x1, x3), t3 = csub(x1, x3);
  float2 it3 = muli(t3);
  x0 = cadd(t0, t2); x2 = csub(t0, t2);
  x1 = cadd(t1, it3); x3 = csub(t1, it3);
}

#define C8f  0.70710678118654752f
#define C16f 0.92387953251128676f
#define S16f 0.38268343236508977f

// inverse DFT16 in registers
__device__ __forceinline__ void dft16i(float2 r[16]) {
  float2 t[16];
#pragma unroll
  for (int b = 0; b < 4; ++b) {
    float2 a0 = r[b], a1 = r[4 + b], a2 = r[8 + b], a3 = r[12 + b];
    dft4i(a0, a1, a2, a3);
    t[b * 4 + 0] = a0; t[b * 4 + 1] = a1; t[b * 4 + 2] = a2; t[b * 4 + 3] = a3;
  }
  const float2 W1 = make_float2(C16f, S16f);
  const float2 W2 = make_float2(C8f, C8f);
  const float2 W3 = make_float2(S16f, C16f);
  const float2 W6 = make_float2(-C8f, C8f);
  const float2 W9 = make_float2(-C16f, -S16f);
  t[5]  = cmul(t[5],  W1);  t[6]  = cmul(t[6],  W2);  t[7]  = cmul(t[7],  W3);
  t[9]  = cmul(t[9],  W2);  t[10] = muli(t[10]);      t[11] = cmul(t[11], W6);
  t[13] = cmul(t[13], W3);  t[14] = cmul(t[14], W6);  t[15] = cmul(t[15], W9);
#pragma unroll
  for (int q = 0; q < 4; ++q) {
    float2 a0 = t[q], a1 = t[4 + q], a2 = t[8 + q], a3 = t[12 + q];
    dft4i(a0, a1, a2, a3);
    r[q] = a0; r[q + 4] = a1; r[q + 8] = a2; r[q + 12] = a3;
  }
}

// apply r[k] *= e^{i k theta} for k=1..15 via recurrence
__device__ __forceinline__ void twiddle16(float2 r[16], float theta) {
  float sn, cs;
  __sincosf(theta, &sn, &cs);
  float2 w = make_float2(cs, sn);
  float2 wk = w;
  r[1] = cmul(r[1], wk);
#pragma unroll
  for (int k = 2; k < 16; ++k) {
    wk = cmul(wk, w);
    r[k] = cmul(r[k], wk);
  }
}

// ---------------------------------------------------------------------------
// 4096-pt inverse FFT (unnormalized, e^{+i}), radix 16^3 in registers.
// Entry: thread t holds r[n1] = x[256*n1 + t].  Exit: r[d] = X[t + 256*d].
// LDS workspace: EXACTLY 4096 float2 (32 KB).  Bank spread via per-row XOR
// swizzle: slot (row k1, col j) -> k1*256 + (j ^ k1); bijective per row, and
// every access phase lands exactly 4 lanes per bank-pair (= wave64-b64
// floor, same distribution as a padded pitch-257/273 scheme).
// Caller must sync before calling if lds fed r.
// ---------------------------------------------------------------------------
__device__ void fft4096_core(float2 r[16], float2* lds, int t) {
  dft16i(r);
  twiddle16(r, 1.53398078788564123e-3f * (float)t);   // 2*pi/4096 * t
#pragma unroll
  for (int k1 = 0; k1 < 16; ++k1) lds[k1 * 256 + (t ^ k1)] = r[k1];
  __syncthreads();
  const int k1 = t & 15, b = t >> 4;
  float2 s[16];
#pragma unroll
  for (int a = 0; a < 16; ++a) s[a] = lds[k1 * 256 + ((16 * a + b) ^ k1)];
  __syncthreads();
  dft16i(s);
  twiddle16(s, 2.45436926061702596e-2f * (float)b);   // 2*pi/256 * b
#pragma unroll
  for (int c = 0; c < 16; ++c) lds[k1 * 256 + ((c * 16 + b) ^ k1)] = s[c];
  __syncthreads();
#pragma unroll
  for (int bb = 0; bb < 16; ++bb) r[bb] = lds[k1 * 256 + ((b * 16 + bb) ^ k1)];
  dft16i(r);
}

// ---------------------------------------------------------------------------
// P1: mask + transpose. W[o][k] (k<2049) -> WT[k][o] (complex float2)
// 64(k) x 32(o) tiles, float2/int2 loads. blockIdx.x==32 handles k=2048.
// ---------------------------------------------------------------------------
__global__ void mask_transpose(const float* __restrict__ wr, const float* __restrict__ wi,
                               const int* __restrict__ zmat, float2* __restrict__ wt) {
  __shared__ float2 tile[32][65];   // [o-local][k-local], pitch 65 -> 2-way (free)
  const int tx = threadIdx.x;       // 0..31
  const int ty = threadIdx.y;       // 0..7
  const int o0 = blockIdx.y * 32;
  if (blockIdx.x == 32) {           // Nyquist column k = 2048
    int t = ty * 32 + tx;
    if (t < 32) {
      int o = o0 + t;
      size_t idx = (size_t)o * IN_N + 2048;
      float2 v = make_float2(0.f, 0.f);
      if (zmat[idx] <= 8388608) v = make_float2(wr[idx], wi[idx]);
      wt[(size_t)2048 * OUT_N + o] = v;
    }
    return;
  }
  const int k0 = blockIdx.x * 64;
#pragma unroll
  for (int r = 0; r < 4; ++r) {
    int o = o0 + ty + r * 8;
    size_t base = (size_t)o * IN_N + k0 + tx * 2;
    float2 vr = *(const float2*)&wr[base];
    float2 vi = *(const float2*)&wi[base];
    int2   z  = *(const int2*)&zmat[base];
    tile[ty + r * 8][tx * 2]     = (z.x <= 8388608) ? make_float2(vr.x, vi.x) : make_float2(0.f, 0.f);
    tile[ty + r * 8][tx * 2 + 1] = (z.y <= 8388608) ? make_float2(vr.y, vi.y) : make_float2(0.f, 0.f);
  }
  __syncthreads();
#pragma unroll
  for (int rr = 0; rr < 8; ++rr) {
    int k = k0 + ty + rr * 8;
    int o = o0 + tx;
    wt[(size_t)k * OUT_N + o] = tile[tx][ty + rr * 8];
  }
}

// ---------------------------------------------------------------------------
// P2': per-row inverse FFT of WT row kk, output written PAIR-PACKED +
// TRANSPOSED: wtp[L][k] (float4 = {Y[k][2L], Y[k][2L+1]}, pitch 2048 f4)
// so P4 reads 32KB CONTIGUOUS per block (R4's strided P4-reads splintered
// 64 lines per wave-load; strided *writes* merge in L2 instead).
// Line-combining: line [L][k0..k0+7] receives 8x16B from blocks k0..k0+7;
// the XCD-chunked grid swizzle kk=(bid&7)*256+(bid>>3) co-locates those 8
// blocks on one XCD/L2 (assumes round-robin dispatch; speed-only).
// Nyquist row k=2048 (bid 2048) writes its full FFT output CONTIGUOUS to a
// 32KB scratch at the head of d_out (read by P4, overwritten by GEMM).
// Per-thread pair-write: o=t+256d -> float2 slot (L*2048+kk)*2+(t&1);
// adjacent even/odd lanes merge into 16B transactions.
// ---------------------------------------------------------------------------
__global__ __launch_bounds__(256) void col_ifft_t(const float2* __restrict__ wt,
                                                  float2* __restrict__ wtp2,
                                                  float2* __restrict__ nyq2) {
  __shared__ float2 lds[4096];
  const int t = threadIdx.x;
  const int bid = (int)blockIdx.x;
  const bool ny = (bid == 2048);
  const int kk = ny ? 2048 : ((bid & 7) * 256 + (bid >> 3));
  const float2* row = wt + (size_t)kk * OUT_N;
  float2 r[16];
#pragma unroll
  for (int n1 = 0; n1 < 16; ++n1) r[n1] = row[n1 * 256 + t];
  fft4096_core(r, lds, t);
  if (!ny) {
    const size_t base = (size_t)kk * 2 + (t & 1);
    const int Lt = t >> 1;
#pragma unroll
    for (int d = 0; d < 16; ++d) {
      size_t L = (size_t)(Lt + 128 * d);
      wtp2[L * 4096 + base] = r[d];      // = (L*2048 + kk)*2 + (t&1)
    }
  } else {
#pragma unroll
    for (int d = 0; d < 16; ++d) nyq2[t + 256 * d] = r[d];   // contiguous 32KB
  }
}

// ---------------------------------------------------------------------------
// P4'': TWO rows per block, reading the pair-packed TRANSPOSED wtp:
// block L needs wtp[L][0..2047] = ONE contiguous 32KB slab (16B/lane
// coalesced), plus the single Nyquist float4 nyq[L] from d_out scratch.
// ifft(Ya_ext + i*Yb_ext) = a + i*b exactly; scale 1/4096^2 covers P2 too.
// ---------------------------------------------------------------------------
__global__ __launch_bounds__(256) void row_irfft2(const float4* __restrict__ wtp,
                                                  const float4* __restrict__ nyq,
                                                  unsigned short* __restrict__ wbf) {
  __shared__ float4 lsf[2048];      // lsf[k] = {Ya.re, Ya.im, Yb.re, Yb.im}
  const int t = threadIdx.x;
  const int L = (int)blockIdx.x;
  const int oa = L * 2, ob = oa + 1;
  const float4* src = wtp + (size_t)L * 2048;
#pragma unroll
  for (int j = 0; j < 8; ++j) {
    int k = t + j * 256;            // 0..2047
    lsf[k] = src[k];                // contiguous, coalesced
  }
  __syncthreads();
  float2 r[16];
#pragma unroll
  for (int n1 = 0; n1 < 16; ++n1) {
    int m = n1 * 256 + t;
    float2 za, zb;
    if (m == 0)        { float4 v = lsf[0];    za = make_float2(v.x, 0.f); zb = make_float2(v.z, 0.f); }
    else if (m < 2048) { float4 v = lsf[m];    za = make_float2(v.x, v.y); zb = make_float2(v.z, v.w); }
    else if (m == 2048){ float4 v = nyq[L];    // Nyquist, single lane per block
                         za = make_float2(v.x, 0.f); zb = make_float2(v.z, 0.f); }
    else { float4 v = lsf[4096 - m];
           za = make_float2(v.x, -v.y); zb = make_float2(v.z, -v.w); }
    r[n1] = make_float2(za.x - zb.y, za.y + zb.x);   // za + i*zb
  }
  __syncthreads();
  fft4096_core(r, (float2*)lsf, t);
  const float sc = 1.0f / (4096.0f * 4096.0f);
  unsigned short* orow_a = wbf + (size_t)oa * IN_N;
  unsigned short* orow_b = wbf + (size_t)ob * IN_N;
#pragma unroll
  for (int d = 0; d < 16; ++d) {
    orow_a[t + 256 * d] = f2bf(r[d].x * sc);
    orow_b[t + 256 * d] = f2bf(r[d].y * sc);
  }
}

// ---------------------------------------------------------------------------
// P5: data f32 -> bf16
// ---------------------------------------------------------------------------
__global__ void cvt_bf16(const float* __restrict__ x, unsigned short* __restrict__ o, int n4) {
  int i = blockIdx.x * blockDim.x + threadIdx.x;
  if (i < n4) {
    float4 v = ((const float4*)x)[i];
    ushort4 r;
    r.x = f2bf(v.x); r.y = f2bf(v.y); r.z = f2bf(v.z); r.w = f2bf(v.w);
    ((ushort4*)o)[i] = r;
  }
}

// ---------------------------------------------------------------------------
// P6: C[M,N] = A[M,K] * B[N,K]^T + bias  (bf16 in, f32 out)
// 256 thr / 4 waves (2x2 of 64x64), 128x128 tile, BK=64, XOR-swizzled LDS.
// Explicit 2-slot double-buffer with COUNTED vmcnt (T3/T4 minimum).
// VALIDATED R2-R4: 90 -> 76 us, MfmaUtil ~39%, conflicts 0.  ~904 TF
// = the known ~900 TF ceiling of the 128^2 2-barrier structure; 8-phase
// 256^2 maps badly (128 WGs on 256 CUs at M=2048).  Do not touch.
// ---------------------------------------------------------------------------
#define BK 64
#define NT (IN_N / BK)

__device__ __forceinline__ void gload_lds16(const void* gp, void* lp) {
  typedef const __attribute__((address_space(1))) void* gptr_t;
  typedef __attribute__((address_space(3))) void* lptr_t;
  __builtin_amdgcn_global_load_lds((gptr_t)(unsigned long long)gp,
                                   (lptr_t)(unsigned int)(unsigned long long)lp,
                                   16, 0, 0);
}

// stage one 128x64 A-tile + B-tile into slot LDS (8 gloads/thread = 8 vmcnt
// ticks/wave; all waves issue uniformly so vmcnt bookkeeping is wave-uniform)
__device__ __forceinline__ void stage_tile(const unsigned short* __restrict__ A,
                                           const unsigned short* __restrict__ B,
                                           unsigned short* as, unsigned short* bs,
                                           int gm0, int gn0, int kt,
                                           int r0, int srow, int schunk) {
#pragma unroll
  for (int j = 0; j < 4; ++j) {
    gload_lds16(A + ((size_t)(gm0 + r0 + j * 8 + srow) * IN_N + kt + schunk * 8),
                as + (size_t)(r0 + j * 8) * BK);
    gload_lds16(B + ((size_t)(gn0 + r0 + j * 8 + srow) * IN_N + kt + schunk * 8),
                bs + (size_t)(r0 + j * 8) * BK);
  }
}

__global__ __launch_bounds__(256) void gemm_bt_bias(const unsigned short* __restrict__ A,
                                                    const unsigned short* __restrict__ B,
                                                    const float* __restrict__ bias,
                                                    float* __restrict__ C) {
  __shared__ __align__(16) unsigned short As[2][128 * BK];   // 2 x 16 KB
  __shared__ __align__(16) unsigned short Bs[2][128 * BK];   // 2 x 16 KB
  const int tid  = threadIdx.x;
  const int wave = tid >> 6;
  const int lane = tid & 63;
  const int gm0 = blockIdx.y * 128;
  const int gn0 = blockIdx.x * 128;

  f32x4 acc[4][4] = {};
  const int wm = wave >> 1, wn = wave & 1;     // 2x2 waves, 64x64 each
  // staging map: dest row r0+ (lane>>3), dest chunk lane&7 gets src chunk ^row
  const int srow   = lane >> 3;                // 0..7
  const int schunk = (lane & 7) ^ srow;        // XOR swizzle
  const int r0     = wave * 32;                // per-wave staging row base
  // fragment map
  const int l7 = lane & 7;
  const int qbase = lane >> 4;                 // 0..3
  const int fra = wm * 64 + (lane & 15);
  const int frb = wn * 64 + (lane & 15);

  // prologue: fill both slots
  stage_tile(A, B, As[0], Bs[0], gm0, gn0, 0,  r0, srow, schunk);
  stage_tile(A, B, As[1], Bs[1], gm0, gn0, BK, r0, srow, schunk);

  for (int t = 0; t < NT; ++t) {
    const int S = t & 1;
    // tile t landed (everything except the newest 8 loads = tile t+1);
    // last iter has nothing in flight behind it -> drain.
    if (t < NT - 1) asm volatile("s_waitcnt vmcnt(8)" ::: "memory");
    else            asm volatile("s_waitcnt vmcnt(0)" ::: "memory");
    __builtin_amdgcn_sched_barrier(0);   // rule #18: pin code motion at the wait
    __builtin_amdgcn_s_barrier();        // raw barrier: no implicit vmcnt(0) drain
    __builtin_amdgcn_sched_barrier(0);

#pragma unroll
    for (int kk = 0; kk < 2; ++kk) {
      bf16x8 af[4], bfr[4];
      const int q = kk * 4 + qbase;            // logical 16B chunk 0..7
#pragma unroll
      for (int i = 0; i < 4; ++i) {
        af[i]  = *(const bf16x8*)&As[S][(fra + i * 16) * BK + ((q ^ l7) * 8)];
        bfr[i] = *(const bf16x8*)&Bs[S][(frb + i * 16) * BK + ((q ^ l7) * 8)];
      }
#pragma unroll
      for (int mi = 0; mi < 4; ++mi)
#pragma unroll
        for (int ni = 0; ni < 4; ++ni)
          acc[mi][ni] = __builtin_amdgcn_mfma_f32_16x16x32_bf16(af[mi], bfr[ni], acc[mi][ni], 0, 0, 0);
    }
    __builtin_amdgcn_sched_barrier(0);
    __builtin_amdgcn_s_barrier();   // all waves done reading slot S
    if (t + 2 < NT)                 // refill the slot just freed
      stage_tile(A, B, As[S], Bs[S], gm0, gn0, (t + 2) * BK, r0, srow, schunk);
  }

  // epilogue: C/D layout col = lane&15, row = (lane>>4)*4 + r   [m89/m91]
  const int col0 = gn0 + wn * 64 + (lane & 15);
  const int row0 = gm0 + wm * 64 + (lane >> 4) * 4;
#pragma unroll
  for (int mi = 0; mi < 4; ++mi) {
#pragma unroll
    for (int ni = 0; ni < 4; ++ni) {
      int col = col0 + ni * 16;
      float bv = bias[col];
#pragma unroll
      for (int r = 0; r < 4; ++r) {
        int row = row0 + mi * 16 + r;
        C[(size_t)row * OUT_N + col] = acc[mi][ni][r] + bv;
      }
    }
  }
}

// ---------------------------------------------------------------------------
// Workspace layout (max 134,250,496 B = exactly the baseline-proven usage):
//   wt  [0,          67,141,632)   2049*4096*8  (float2)       dead after P2
//   wtp [67,141,632, 134,250,496)  2048*2048*16 (float4 pairs) P2 out, P4 in
//   wbf [0,          33,554,432)   4096*4096*2  overlays dead wt (P4 writes)
//   dbf [33,554,432, 50,331,648)   2048*4096*2  overlays dead wt (P5 writes)
//   nyq: 32 KB scratch at head of d_out (P2 writes, P4 reads, GEMM overwrites)
// ---------------------------------------------------------------------------
extern "C" void kernel_launch(void* const* d_in, const int* in_sizes, int n_in,
                              void* d_out, int out_size, void* d_ws, size_t ws_size,
                              hipStream_t stream) {
  const float* data = (const float*)d_in[0];
  const float* wr   = (const float*)d_in[1];
  const float* wi   = (const float*)d_in[2];
  const float* bias = (const float*)d_in[3];
  const int*   zmat = (const int*)d_in[4];

  char* ws = (char*)d_ws;
  float2* wt  = (float2*)ws;                                  // 2049*4096*8
  float4* wtp = (float4*)(ws + 67141632ull);                  // 2048*2048*16
  unsigned short* wbf = (unsigned short*)ws;                  // overlay dead wt
  unsigned short* dbf = (unsigned short*)(ws + 33554432ull);  // overlay dead wt
  float2* nyq2 = (float2*)d_out;                              // 32KB scratch

  hipLaunchKernelGGL(mask_transpose, dim3(33, 128), dim3(32, 8), 0, stream, wr, wi, zmat, wt);
  hipLaunchKernelGGL(col_ifft_t,     dim3(2049),    dim3(256),   0, stream, wt, (float2*)wtp, nyq2);
  hipLaunchKernelGGL(row_irfft2,     dim3(2048),    dim3(256),   0, stream, wtp, (const float4*)d_out, wbf);
  hipLaunchKernelGGL(cvt_bf16,       dim3(8192),    dim3(256),   0, stream, data, dbf, (BATCH * IN_N) / 4);
  hipLaunchKernelGGL(gemm_bt_bias,   dim3(OUT_N / 128, BATCH / 128), dim3(256), 0, stream,
                     dbf, wbf, bias, (float*)d_out);
}

// Round 6
// 330.865 us; speedup vs baseline: 1.0578x; 1.0578x over previous
//
#include <hip/hip_runtime.h>
#include <hip/hip_bf16.h>
#include <stdint.h>

#define OUT_N 4096
#define IN_N  4096
#define BATCH 2048
#define KHALF 2049   // IN/2 + 1

typedef __bf16 bf16x8 __attribute__((ext_vector_type(8)));
typedef float  f32x4  __attribute__((ext_vector_type(4)));

__device__ __forceinline__ unsigned short f2bf(float f) {
  unsigned int u = __builtin_bit_cast(unsigned int, f);
  u += 0x7FFFu + ((u >> 16) & 1u);   // round-to-nearest-even
  return (unsigned short)(u >> 16);
}

// ---------------------------------------------------------------------------
// complex helpers
// ---------------------------------------------------------------------------
__device__ __forceinline__ float2 cmul(float2 a, float2 b) {
  return make_float2(a.x * b.x - a.y * b.y, a.x * b.y + a.y * b.x);
}
__device__ __forceinline__ float2 cadd(float2 a, float2 b) { return make_float2(a.x + b.x, a.y + b.y); }
__device__ __forceinline__ float2 csub(float2 a, float2 b) { return make_float2(a.x - b.x, a.y - b.y); }
__device__ __forceinline__ float2 muli(float2 a) { return make_float2(-a.y, a.x); }  // *e^{+i pi/2}

// inverse DFT4 (w = +i)
__device__ __forceinline__ void dft4i(float2& x0, float2& x1, float2& x2, float2& x3) {
  float2 t0 = cadd(x0, x2), t1 = csub(x0, x2);
  float2 t2 = cadd(x1, x3), t3 = csub(x1, x3);
  float2 it3 = muli(t3);
  x0 = cadd(t0, t2); x2 = csub(t0, t2);
  x1 = cadd(t1, it3); x3 = csub(t1, it3);
}

#define C8f  0.70710678118654752f
#define C16f 0.92387953251128676f
#define S16f 0.38268343236508977f

// inverse DFT16 in registers
__device__ __forceinline__ void dft16i(float2 r[16]) {
  float2 t[16];
#pragma unroll
  for (int b = 0; b < 4; ++b) {
    float2 a0 = r[b], a1 = r[4 + b], a2 = r[8 + b], a3 = r[12 + b];
    dft4i(a0, a1, a2, a3);
    t[b * 4 + 0] = a0; t[b * 4 + 1] = a1; t[b * 4 + 2] = a2; t[b * 4 + 3] = a3;
  }
  const float2 W1 = make_float2(C16f, S16f);
  const float2 W2 = make_float2(C8f, C8f);
  const float2 W3 = make_float2(S16f, C16f);
  const float2 W6 = make_float2(-C8f, C8f);
  const float2 W9 = make_float2(-C16f, -S16f);
  t[5]  = cmul(t[5],  W1);  t[6]  = cmul(t[6],  W2);  t[7]  = cmul(t[7],  W3);
  t[9]  = cmul(t[9],  W2);  t[10] = muli(t[10]);      t[11] = cmul(t[11], W6);
  t[13] = cmul(t[13], W3);  t[14] = cmul(t[14], W6);  t[15] = cmul(t[15], W9);
#pragma unroll
  for (int q = 0; q < 4; ++q) {
    float2 a0 = t[q], a1 = t[4 + q], a2 = t[8 + q], a3 = t[12 + q];
    dft4i(a0, a1, a2, a3);
    r[q] = a0; r[q + 4] = a1; r[q + 8] = a2; r[q + 12] = a3;
  }
}

// apply r[k] *= e^{i k theta} for k=1..15 via recurrence
__device__ __forceinline__ void twiddle16(float2 r[16], float theta) {
  float sn, cs;
  __sincosf(theta, &sn, &cs);
  float2 w = make_float2(cs, sn);
  float2 wk = w;
  r[1] = cmul(r[1], wk);
#pragma unroll
  for (int k = 2; k < 16; ++k) {
    wk = cmul(wk, w);
    r[k] = cmul(r[k], wk);
  }
}

// ---------------------------------------------------------------------------
// 4096-pt inverse FFT (unnormalized, e^{+i}), radix 16^3 in registers.
// Entry: thread t holds r[n1] = x[256*n1 + t].  Exit: r[d] = X[t + 256*d].
// LDS workspace: EXACTLY 4096 float2 (32 KB).  Bank spread via per-row XOR
// swizzle: slot (row k1, col j) -> k1*256 + (j ^ k1); bijective per row, and
// every access phase lands exactly 4 lanes per bank-pair (= wave64-b64
// floor, same distribution as a padded pitch-257/273 scheme).
// Caller must sync before calling if lds fed r.
// ---------------------------------------------------------------------------
__device__ void fft4096_core(float2 r[16], float2* lds, int t) {
  dft16i(r);
  twiddle16(r, 1.53398078788564123e-3f * (float)t);   // 2*pi/4096 * t
#pragma unroll
  for (int k1 = 0; k1 < 16; ++k1) lds[k1 * 256 + (t ^ k1)] = r[k1];
  __syncthreads();
  const int k1 = t & 15, b = t >> 4;
  float2 s[16];
#pragma unroll
  for (int a = 0; a < 16; ++a) s[a] = lds[k1 * 256 + ((16 * a + b) ^ k1)];
  __syncthreads();
  dft16i(s);
  twiddle16(s, 2.45436926061702596e-2f * (float)b);   // 2*pi/256 * b
#pragma unroll
  for (int c = 0; c < 16; ++c) lds[k1 * 256 + ((c * 16 + b) ^ k1)] = s[c];
  __syncthreads();
#pragma unroll
  for (int bb = 0; bb < 16; ++bb) r[bb] = lds[k1 * 256 + ((b * 16 + bb) ^ k1)];
  dft16i(r);
}

// ---------------------------------------------------------------------------
// P1: mask + transpose. W[o][k] (k<2049) -> WT[k][o] (complex float2)
// 64(k) x 32(o) tiles, float2/int2 loads. blockIdx.x==32 handles k=2048.
// ---------------------------------------------------------------------------
__global__ void mask_transpose(const float* __restrict__ wr, const float* __restrict__ wi,
                               const int* __restrict__ zmat, float2* __restrict__ wt) {
  __shared__ float2 tile[32][65];   // [o-local][k-local], pitch 65 -> 2-way (free)
  const int tx = threadIdx.x;       // 0..31
  const int ty = threadIdx.y;       // 0..7
  const int o0 = blockIdx.y * 32;
  if (blockIdx.x == 32) {           // Nyquist column k = 2048
    int t = ty * 32 + tx;
    if (t < 32) {
      int o = o0 + t;
      size_t idx = (size_t)o * IN_N + 2048;
      float2 v = make_float2(0.f, 0.f);
      if (zmat[idx] <= 8388608) v = make_float2(wr[idx], wi[idx]);
      wt[(size_t)2048 * OUT_N + o] = v;
    }
    return;
  }
  const int k0 = blockIdx.x * 64;
#pragma unroll
  for (int r = 0; r < 4; ++r) {
    int o = o0 + ty + r * 8;
    size_t base = (size_t)o * IN_N + k0 + tx * 2;
    float2 vr = *(const float2*)&wr[base];
    float2 vi = *(const float2*)&wi[base];
    int2   z  = *(const int2*)&zmat[base];
    tile[ty + r * 8][tx * 2]     = (z.x <= 8388608) ? make_float2(vr.x, vi.x) : make_float2(0.f, 0.f);
    tile[ty + r * 8][tx * 2 + 1] = (z.y <= 8388608) ? make_float2(vr.y, vi.y) : make_float2(0.f, 0.f);
  }
  __syncthreads();
#pragma unroll
  for (int rr = 0; rr < 8; ++rr) {
    int k = k0 + ty + rr * 8;
    int o = o0 + tx;
    wt[(size_t)k * OUT_N + o] = tile[tx][ty + rr * 8];
  }
}

// ---------------------------------------------------------------------------
// P2: per-row inverse FFT of WT, in place, UNnormalized (1/4096^2 in P4)
// No min-waves clause (R2's (256,5) cap regressed ~50 us — spill suspect).
// ---------------------------------------------------------------------------
__global__ __launch_bounds__(256) void col_ifft(float2* __restrict__ wt) {
  __shared__ float2 lds[4096];
  const int t = threadIdx.x;
  float2* row = wt + (size_t)blockIdx.x * OUT_N;
  float2 r[16];
#pragma unroll
  for (int n1 = 0; n1 < 16; ++n1) r[n1] = row[n1 * 256 + t];
  fft4096_core(r, lds, t);
#pragma unroll
  for (int d = 0; d < 16; ++d) row[t + 256 * d] = r[d];
}

// ---------------------------------------------------------------------------
// P4': TWO rows per block, reading WT[k][o] DIRECTLY (proven R4 pattern).
// Rows oa=2L, ob=2L+1 adjacent in o -> one float4 load per k fetches both
// rows' element k: wt4[k*2048 + L].  XCD-chunked swizzle lb=(bid&7)*256+
// (bid>>3) co-locates the 8 L-blocks sharing each 128B line on one XCD/L2.
// R5 lesson: moving this splinter to P2's write side is NOT cheaper.
// ifft(Ya_ext + i*Yb_ext) = a + i*b exactly; scale 1/4096^2 covers P2 too.
// FUSED P5 TAIL: after the wbf stores, each block converts its 4096-float
// chunk of `data` to bf16 (4 float4/thread) — removes the standalone
// cvt_bf16 launch; BW work rides in P4's tail stagger.
// ---------------------------------------------------------------------------
__global__ __launch_bounds__(256) void row_irfft2(const float2* __restrict__ wt,
                                                  unsigned short* __restrict__ wbf,
                                                  const float* __restrict__ data,
                                                  unsigned short* __restrict__ dbf) {
  __shared__ float4 lsf[2048];      // lsf[k] = {Ya.re, Ya.im, Yb.re, Yb.im}
  const int t = threadIdx.x;
  const int bid = (int)blockIdx.x;
  const int lb  = (bid & 7) * 256 + (bid >> 3);   // XCD-chunked logical block
  const int oa = lb * 2, ob = oa + 1;
  const float4* wt4 = (const float4*)wt;          // wt4[k*2048 + oa/2]
  const int oq = oa >> 1;
#pragma unroll
  for (int j = 0; j < 8; ++j) {
    int k = t + j * 256;            // 0..2047
    lsf[k] = wt4[(size_t)k * 2048 + oq];
  }
  __syncthreads();
  float2 r[16];
#pragma unroll
  for (int n1 = 0; n1 < 16; ++n1) {
    int m = n1 * 256 + t;
    float2 za, zb;
    if (m == 0)        { float4 v = lsf[0];    za = make_float2(v.x, 0.f); zb = make_float2(v.z, 0.f); }
    else if (m < 2048) { float4 v = lsf[m];    za = make_float2(v.x, v.y); zb = make_float2(v.z, v.w); }
    else if (m == 2048){ float4 v = wt4[(size_t)2048 * 2048 + oq];   // Nyquist, single lane
                         za = make_float2(v.x, 0.f); zb = make_float2(v.z, 0.f); }
    else { float4 v = lsf[4096 - m];
           za = make_float2(v.x, -v.y); zb = make_float2(v.z, -v.w); }
    r[n1] = make_float2(za.x - zb.y, za.y + zb.x);   // za + i*zb
  }
  __syncthreads();
  fft4096_core(r, (float2*)lsf, t);
  const float sc = 1.0f / (4096.0f * 4096.0f);
  unsigned short* orow_a = wbf + (size_t)oa * IN_N;
  unsigned short* orow_b = wbf + (size_t)ob * IN_N;
#pragma unroll
  for (int d = 0; d < 16; ++d) {
    orow_a[t + 256 * d] = f2bf(r[d].x * sc);
    orow_b[t + 256 * d] = f2bf(r[d].y * sc);
  }
  // ---- fused P5: data f32 -> bf16, 4096 floats per block (by raw bid) ----
  const float4* dsrc = (const float4*)data + (size_t)bid * 1024;
  ushort4*      ddst = (ushort4*)dbf + (size_t)bid * 1024;
#pragma unroll
  for (int j = 0; j < 4; ++j) {
    float4 v = dsrc[t + j * 256];
    ushort4 q;
    q.x = f2bf(v.x); q.y = f2bf(v.y); q.z = f2bf(v.z); q.w = f2bf(v.w);
    ddst[t + j * 256] = q;
  }
}

// ---------------------------------------------------------------------------
// P6: C[M,N] = A[M,K] * B[N,K]^T + bias  (bf16 in, f32 out)
// 256 thr / 4 waves (2x2 of 64x64), 128x128 tile, BK=64, XOR-swizzled LDS.
// Explicit 2-slot double-buffer with COUNTED vmcnt (T3/T4 minimum).
// VALIDATED R2-R5: 90 -> 76 us, MfmaUtil ~39%, conflicts 0.  ~904 TF
// = the known ~900 TF ceiling of the 128^2 2-barrier structure; 8-phase
// 256^2 maps badly (128 WGs on 256 CUs at M=2048).  Do not touch.
// ---------------------------------------------------------------------------
#define BK 64
#define NT (IN_N / BK)

__device__ __forceinline__ void gload_lds16(const void* gp, void* lp) {
  typedef const __attribute__((address_space(1))) void* gptr_t;
  typedef __attribute__((address_space(3))) void* lptr_t;
  __builtin_amdgcn_global_load_lds((gptr_t)(unsigned long long)gp,
                                   (lptr_t)(unsigned int)(unsigned long long)lp,
                                   16, 0, 0);
}

// stage one 128x64 A-tile + B-tile into slot LDS (8 gloads/thread = 8 vmcnt
// ticks/wave; all waves issue uniformly so vmcnt bookkeeping is wave-uniform)
__device__ __forceinline__ void stage_tile(const unsigned short* __restrict__ A,
                                           const unsigned short* __restrict__ B,
                                           unsigned short* as, unsigned short* bs,
                                           int gm0, int gn0, int kt,
                                           int r0, int srow, int schunk) {
#pragma unroll
  for (int j = 0; j < 4; ++j) {
    gload_lds16(A + ((size_t)(gm0 + r0 + j * 8 + srow) * IN_N + kt + schunk * 8),
                as + (size_t)(r0 + j * 8) * BK);
    gload_lds16(B + ((size_t)(gn0 + r0 + j * 8 + srow) * IN_N + kt + schunk * 8),
                bs + (size_t)(r0 + j * 8) * BK);
  }
}

__global__ __launch_bounds__(256) void gemm_bt_bias(const unsigned short* __restrict__ A,
                                                    const unsigned short* __restrict__ B,
                                                    const float* __restrict__ bias,
                                                    float* __restrict__ C) {
  __shared__ __align__(16) unsigned short As[2][128 * BK];   // 2 x 16 KB
  __shared__ __align__(16) unsigned short Bs[2][128 * BK];   // 2 x 16 KB
  const int tid  = threadIdx.x;
  const int wave = tid >> 6;
  const int lane = tid & 63;
  const int gm0 = blockIdx.y * 128;
  const int gn0 = blockIdx.x * 128;

  f32x4 acc[4][4] = {};
  const int wm = wave >> 1, wn = wave & 1;     // 2x2 waves, 64x64 each
  // staging map: dest row r0+ (lane>>3), dest chunk lane&7 gets src chunk ^row
  const int srow   = lane >> 3;                // 0..7
  const int schunk = (lane & 7) ^ srow;        // XOR swizzle
  const int r0     = wave * 32;                // per-wave staging row base
  // fragment map
  const int l7 = lane & 7;
  const int qbase = lane >> 4;                 // 0..3
  const int fra = wm * 64 + (lane & 15);
  const int frb = wn * 64 + (lane & 15);

  // prologue: fill both slots
  stage_tile(A, B, As[0], Bs[0], gm0, gn0, 0,  r0, srow, schunk);
  stage_tile(A, B, As[1], Bs[1], gm0, gn0, BK, r0, srow, schunk);

  for (int t = 0; t < NT; ++t) {
    const int S = t & 1;
    // tile t landed (everything except the newest 8 loads = tile t+1);
    // last iter has nothing in flight behind it -> drain.
    if (t < NT - 1) asm volatile("s_waitcnt vmcnt(8)" ::: "memory");
    else            asm volatile("s_waitcnt vmcnt(0)" ::: "memory");
    __builtin_amdgcn_sched_barrier(0);   // rule #18: pin code motion at the wait
    __builtin_amdgcn_s_barrier();        // raw barrier: no implicit vmcnt(0) drain
    __builtin_amdgcn_sched_barrier(0);

#pragma unroll
    for (int kk = 0; kk < 2; ++kk) {
      bf16x8 af[4], bfr[4];
      const int q = kk * 4 + qbase;            // logical 16B chunk 0..7
#pragma unroll
      for (int i = 0; i < 4; ++i) {
        af[i]  = *(const bf16x8*)&As[S][(fra + i * 16) * BK + ((q ^ l7) * 8)];
        bfr[i] = *(const bf16x8*)&Bs[S][(frb + i * 16) * BK + ((q ^ l7) * 8)];
      }
#pragma unroll
      for (int mi = 0; mi < 4; ++mi)
#pragma unroll
        for (int ni = 0; ni < 4; ++ni)
          acc[mi][ni] = __builtin_amdgcn_mfma_f32_16x16x32_bf16(af[mi], bfr[ni], acc[mi][ni], 0, 0, 0);
    }
    __builtin_amdgcn_sched_barrier(0);
    __builtin_amdgcn_s_barrier();   // all waves done reading slot S
    if (t + 2 < NT)                 // refill the slot just freed
      stage_tile(A, B, As[S], Bs[S], gm0, gn0, (t + 2) * BK, r0, srow, schunk);
  }

  // epilogue: C/D layout col = lane&15, row = (lane>>4)*4 + r   [m89/m91]
  const int col0 = gn0 + wn * 64 + (lane & 15);
  const int row0 = gm0 + wm * 64 + (lane >> 4) * 4;
#pragma unroll
  for (int mi = 0; mi < 4; ++mi) {
#pragma unroll
    for (int ni = 0; ni < 4; ++ni) {
      int col = col0 + ni * 16;
      float bv = bias[col];
#pragma unroll
      for (int r = 0; r < 4; ++r) {
        int row = row0 + mi * 16 + r;
        C[(size_t)row * OUT_N + col] = acc[mi][ni][r] + bv;
      }
    }
  }
}

// ---------------------------------------------------------------------------
// Workspace layout (R4-proven; wt stays LIVE through P4 -> wbf must not
// overlay it):
//   wt  [0,          67,141,632)   2049*4096*8  (float2)
//   wbf [67,141,632, 100,696,064)  4096*4096*2  (bf16)
//   dbf [100,696,064, 117,473,280) 2048*4096*2  (bf16)
// ---------------------------------------------------------------------------
extern "C" void kernel_launch(void* const* d_in, const int* in_sizes, int n_in,
                              void* d_out, int out_size, void* d_ws, size_t ws_size,
                              hipStream_t stream) {
  const float* data = (const float*)d_in[0];
  const float* wr   = (const float*)d_in[1];
  const float* wi   = (const float*)d_in[2];
  const float* bias = (const float*)d_in[3];
  const int*   zmat = (const int*)d_in[4];

  char* ws = (char*)d_ws;
  float2* wt = (float2*)ws;                                   // 2049*4096*8
  unsigned short* wbf = (unsigned short*)(ws + 67141632ull);  // 4096*4096*2
  unsigned short* dbf = (unsigned short*)(ws + 100696064ull); // 2048*4096*2

  hipLaunchKernelGGL(mask_transpose, dim3(33, 128), dim3(32, 8), 0, stream, wr, wi, zmat, wt);
  hipLaunchKernelGGL(col_ifft,       dim3(2049),    dim3(256),   0, stream, wt);
  hipLaunchKernelGGL(row_irfft2,     dim3(2048),    dim3(256),   0, stream, wt, wbf, data, dbf);
  hipLaunchKernelGGL(gemm_bt_bias,   dim3(OUT_N / 128, BATCH / 128), dim3(256), 0, stream,
                     dbf, wbf, bias, (float*)d_out);
}